// Round 7
// baseline (181.285 us; speedup 1.0000x reference)
//
#include <hip/hip_runtime.h>
#include <hip/hip_bf16.h>

typedef _Float16 f16;
typedef __attribute__((ext_vector_type(2))) _Float16 f16x2;
typedef __attribute__((ext_vector_type(8))) _Float16 f16x8;
typedef __attribute__((ext_vector_type(16))) float f32x16;

#define BNSCL 0.9999950000375f   /* 1/sqrt(1+1e-5) */

// ---------------------------------------------------------------------------
// Kernel 1: per-point scores MLP + softmax (weights in LDS, 2 pts/thread),
// output f16x8 per point. Fused: blocks < 256 also build wbtA = weight bank
// in MFMA A-fragment order, f16:
//   wbtA[((ot*64 + ks)*64 + lane)*8 + j] = wb[c'][m=j][o]
//   with c' = ks*2 + (lane>>5), o = ot*32 + (lane&31).
// ---------------------------------------------------------------------------
__global__ __launch_bounds__(256) void k_scores(
    const float* __restrict__ xyz,
    const float* __restrict__ w1, const float* __restrict__ g1, const float* __restrict__ be1,
    const float* __restrict__ w2, const float* __restrict__ g2, const float* __restrict__ be2,
    const float* __restrict__ w3, const float* __restrict__ g3, const float* __restrict__ be3,
    const float* __restrict__ w4, const float* __restrict__ b4,
    const float* __restrict__ wb, f16* __restrict__ wbtA,
    f16* __restrict__ scores)
{
    __shared__ float lw[856];
    const int tid = threadIdx.x;

    // fused weight-bank fragment-order transpose (1 elem/thread, blocks 0-255)
    if (blockIdx.x < 256) {
        int idx = blockIdx.x * 256 + tid;       // 0..65535
        int j    = idx & 7;
        int lane = (idx >> 3) & 63;
        int ks   = (idx >> 9) & 63;
        int ot   = idx >> 15;
        int cp   = ks * 2 + (lane >> 5);        // 0..127
        int o    = ot * 32 + (lane & 31);
        wbtA[idx] = (f16)wb[(cp * 8 + j) * 64 + o];
    }

    if (tid < 112) lw[tid] = w1[tid];
    lw[112 + tid] = w2[tid];
    lw[368 + tid] = w3[tid];
    if (tid < 128) lw[624 + tid] = w4[tid];
    if (tid < 8)   lw[752 + tid] = b4[tid];
    if (tid < 16) {
        lw[760 + tid] = g1[tid] * BNSCL;  lw[776 + tid] = be1[tid];
        lw[792 + tid] = g2[tid] * BNSCL;  lw[808 + tid] = be2[tid];
        lw[824 + tid] = g3[tid] * BNSCL;  lw[840 + tid] = be3[tid];
    }
    __syncthreads();

    float in7[2][7], h1[2][16], h2[2][16], s[2][8];

#pragma unroll
    for (int q = 0; q < 2; ++q) {
        int g = blockIdx.x * 512 + q * 256 + tid;
        int b = g >> 15;
        int p = g & 32767;
        int pc = p & ~31;
        const float* xb = xyz + (size_t)b * 98304;
        float cx = xb[pc], cy = xb[32768 + pc], cz = xb[65536 + pc];
        float dx = xb[p] - cx, dy = xb[32768 + p] - cy, dz = xb[65536 + p] - cz;
        in7[q][0] = cx; in7[q][1] = cy; in7[q][2] = cz;
        in7[q][3] = dx; in7[q][4] = dy; in7[q][5] = dz;
        in7[q][6] = sqrtf(dx * dx + dy * dy + dz * dz);
    }

#pragma unroll
    for (int o = 0; o < 16; ++o) {
        float a0 = 0.f, a1 = 0.f;
#pragma unroll
        for (int c = 0; c < 7; ++c) {
            float w = lw[o * 7 + c];
            a0 += w * in7[0][c]; a1 += w * in7[1][c];
        }
        float gs = lw[760 + o], bb = lw[776 + o];
        h1[0][o] = fmaxf(a0 * gs + bb, 0.f);
        h1[1][o] = fmaxf(a1 * gs + bb, 0.f);
    }
#pragma unroll
    for (int o = 0; o < 16; ++o) {
        float a0 = 0.f, a1 = 0.f;
#pragma unroll
        for (int c = 0; c < 16; ++c) {
            float w = lw[112 + o * 16 + c];
            a0 += w * h1[0][c]; a1 += w * h1[1][c];
        }
        float gs = lw[792 + o], bb = lw[808 + o];
        h2[0][o] = fmaxf(a0 * gs + bb, 0.f);
        h2[1][o] = fmaxf(a1 * gs + bb, 0.f);
    }
#pragma unroll
    for (int o = 0; o < 16; ++o) {
        float a0 = 0.f, a1 = 0.f;
#pragma unroll
        for (int c = 0; c < 16; ++c) {
            float w = lw[368 + o * 16 + c];
            a0 += w * h2[0][c]; a1 += w * h2[1][c];
        }
        float gs = lw[824 + o], bb = lw[840 + o];
        h1[0][o] = fmaxf(a0 * gs + bb, 0.f);
        h1[1][o] = fmaxf(a1 * gs + bb, 0.f);
    }
#pragma unroll
    for (int o = 0; o < 8; ++o) {
        float bb = lw[752 + o];
        float a0 = bb, a1 = bb;
#pragma unroll
        for (int c = 0; c < 16; ++c) {
            float w = lw[624 + o * 16 + c];
            a0 += w * h1[0][c]; a1 += w * h1[1][c];
        }
        s[0][o] = a0; s[1][o] = a1;
    }

#pragma unroll
    for (int q = 0; q < 2; ++q) {
        int g = blockIdx.x * 512 + q * 256 + tid;
        float mx = s[q][0];
#pragma unroll
        for (int i = 1; i < 8; ++i) mx = fmaxf(mx, s[q][i]);
        float sum = 0.f;
#pragma unroll
        for (int i = 0; i < 8; ++i) { s[q][i] = __expf(s[q][i] - mx); sum += s[q][i]; }
        float inv = 1.f / sum;
        f16x8 o8;
#pragma unroll
        for (int i = 0; i < 8; ++i) o8[i] = (f16)(s[q][i] * inv);
        *(f16x8*)(scores + (size_t)g * 8) = o8;
    }
}

// ---------------------------------------------------------------------------
// Kernel 2: main einsum, 32x32x16 f16 MFMA.
// ROUND 7: phase-lockstep break. Five schedules (r0,2,4,5,6) all plateau at
// 52-56 us with LDS ~33% + VALU ~27% + MFMA ~25% summing to ~the whole wall:
// the three units are used SEQUENTIALLY because all 4 waves/SIMD run
// identical instruction streams from a common barrier (WAITVs never block in
// steady state, nothing desynchronizes) -> every wave is in the same phase,
// each unit idles ~70% by ALIGNMENT, not lack of work. m114 proves gfx950
// co-issues different pipes from different waves when phases differ.
// Fix A: per-wave s_sleep stagger (512/1024/1536 cyc) AFTER the weights
// barrier; key (wave>>2)^(wave&3) staggers SIMD-siblings under either
// wave->SIMD mapping; offsets persist (no loop re-sync).
// Fix B: T5 s_setprio(1) around each MFMA cluster - pays exactly when waves
// have role diversity, which the stagger creates.
// Everything else byte-identical to round 6 (distance-6 DMA pipeline).
// ---------------------------------------------------------------------------
__global__ __launch_bounds__(1024, 4) void k_main(
    const float* __restrict__ feat,
    const f16* __restrict__ scores,
    const f16* __restrict__ wbtA,
    const float* __restrict__ bn_g, const float* __restrict__ bn_b,
    float* __restrict__ out)
{
    __shared__ __align__(16) f16 lwb[32768];         // 64 KB weights
    __shared__ __align__(16) float fbuf[8][2][1024]; // 64 KB feat 8-slot buf

    const int tid  = threadIdx.x;
    const int lane = tid & 63;
    const int wave = tid >> 6;          // 0..15
    const int l31  = lane & 31;
    const int lh   = lane >> 5;         // 0..1
    const int w64  = wave * 64;

    const int ot = blockIdx.x >> 8;             // 0..1 (o-tile half)
    const int g  = blockIdx.x & 255;            // point-group
    const int pblock = g * 1024;                // global point base
    const int b    = pblock >> 15;
    const int pt0  = (pblock & 32767) + w64;    // within-batch, 32-aligned
    const int pc0  = pt0 + l31;
    const int pc1  = pc0 + 32;

    const float* fb = feat + (size_t)b * 2097152;    // (64, 32768)
    // per-lane DMA source base: this wave's 64-pt window, row 0
    const float* gsrc0 = fb + (pblock & 32767) + w64 + lane;

    // ---- stage this ot's 64 KB of fragment-ordered weights into LDS ----
    const f16* src = wbtA + ((size_t)ot << 15);      // 32768 f16
#pragma unroll
    for (int it = 0; it < 4; ++it) {
        int idx = it * 1024 + tid;                   // 0..4095 16B-chunks
        *(int4*)&lwb[idx << 3] = *(const int4*)&src[idx << 3];
    }

    // ---- scores: load + extract to registers (consumed before loop) ----
    const int gpt = pblock + w64 + l31;
    f16x8 sv0 = *(const f16x8*)(scores + (size_t)gpt * 8);
    f16x8 sv1 = *(const f16x8*)(scores + (size_t)(gpt + 32) * 8);
    const f16x2 s0a = {sv0[0], sv0[1]}, s0b = {sv0[2], sv0[3]},
                s0c = {sv0[4], sv0[5]}, s0d = {sv0[6], sv0[7]};
    const f16x2 s1a = {sv1[0], sv1[1]}, s1b = {sv1[2], sv1[3]},
                s1c = {sv1[4], sv1[5]}, s1d = {sv1[6], sv1[7]};

    f32x16 acc0 = {}, acc1 = {};
    const f16* Alds = lwb + (lane << 3);             // lane's 16B slot

// DMA one kk-step's feat tile (rows 2kk, 2kk+1; this wave's 64 points) into
// fbuf[kk & 7]. Wave-uniform LDS dest + lane*4; per-lane global src.
#define STAGE(t)                                                               \
    {                                                                          \
        __builtin_amdgcn_global_load_lds(                                      \
            (const __attribute__((address_space(1))) void*)                    \
                (gsrc0 + ((size_t)(2 * (t)) << 15)),                           \
            (__attribute__((address_space(3))) void*)&fbuf[(t) & 7][0][w64],   \
            4, 0, 0);                                                          \
        __builtin_amdgcn_global_load_lds(                                      \
            (const __attribute__((address_space(1))) void*)                    \
                (gsrc0 + ((size_t)(2 * (t) + 1) << 15)),                       \
            (__attribute__((address_space(3))) void*)&fbuf[(t) & 7][1][w64],   \
            4, 0, 0);                                                          \
    }

#define WAITV(n) asm volatile("s_waitcnt vmcnt(" #n ")" ::: "memory")

    // keep pre-loop loads/extracts above; then prologue DMA tiles 0..5
    __builtin_amdgcn_sched_barrier(0);
    STAGE(0); STAGE(1); STAGE(2); STAGE(3); STAGE(4); STAGE(5);

    // weights visible to all waves; prologue DMAs stay in flight (raw barrier)
    asm volatile("s_waitcnt lgkmcnt(0)" ::: "memory");
    __builtin_amdgcn_s_barrier();

    // ---- phase stagger: desync the 4 SIMD-sibling waves (~1/4 iter each).
    // Key works under both plausible wave->SIMD mappings (i%4 and i/4).
    {
        int dkey = ((wave >> 2) ^ (wave & 3));
        if (dkey == 1)      asm volatile("s_sleep 8");
        else if (dkey == 2) asm volatile("s_sleep 16");
        else if (dkey == 3) asm volatile("s_sleep 24");
    }

// one compute iteration (no fences inside) -------------------------------
#define KSTEP(kk)                                                              \
    {                                                                          \
        f16x8 aD = *(const f16x8*)(Alds + ((size_t)(kk) << 9));                \
        f16x8 aR = *(const f16x8*)(Alds + ((size_t)((kk) + 32) << 9));         \
        const float* frow = fbuf[(kk) & 7][lh];                                \
        float fv0 = frow[w64 + l31], fv1 = frow[w64 + l31 + 32];               \
        float fc0 = frow[w64],       fc1 = frow[w64 + 32];                     \
        f16 hR0 = (f16)fv0,          hR1 = (f16)fv1;                           \
        f16 hD0 = (f16)(fv0 - fc0),  hD1 = (f16)(fv1 - fc1);                   \
        f16x2 fR0 = {hR0, hR0}, fR1 = {hR1, hR1};                              \
        f16x2 fD0 = {hD0, hD0}, fD1 = {hD1, hD1};                              \
        f16x2 d0a = fD0 * s0a, d0b = fD0 * s0b, d0c = fD0 * s0c, d0d = fD0 * s0d; \
        f16x2 d1a = fD1 * s1a, d1b = fD1 * s1b, d1c = fD1 * s1c, d1d = fD1 * s1d; \
        f16x2 r0a = fR0 * s0a, r0b = fR0 * s0b, r0c = fR0 * s0c, r0d = fR0 * s0d; \
        f16x2 r1a = fR1 * s1a, r1b = fR1 * s1b, r1c = fR1 * s1c, r1d = fR1 * s1d; \
        f16x8 bD0 = {d0a[0],d0a[1],d0b[0],d0b[1],d0c[0],d0c[1],d0d[0],d0d[1]}; \
        f16x8 bD1 = {d1a[0],d1a[1],d1b[0],d1b[1],d1c[0],d1c[1],d1d[0],d1d[1]}; \
        f16x8 bR0 = {r0a[0],r0a[1],r0b[0],r0b[1],r0c[0],r0c[1],r0d[0],r0d[1]}; \
        f16x8 bR1 = {r1a[0],r1a[1],r1b[0],r1b[1],r1c[0],r1c[1],r1d[0],r1d[1]}; \
        __builtin_amdgcn_s_setprio(1);                                         \
        acc0 = __builtin_amdgcn_mfma_f32_32x32x16_f16(aD, bD0, acc0, 0, 0, 0); \
        acc1 = __builtin_amdgcn_mfma_f32_32x32x16_f16(aD, bD1, acc1, 0, 0, 0); \
        acc0 = __builtin_amdgcn_mfma_f32_32x32x16_f16(aR, bR0, acc0, 0, 0, 0); \
        acc1 = __builtin_amdgcn_mfma_f32_32x32x16_f16(aR, bR1, acc1, 0, 0, 0); \
        __builtin_amdgcn_s_setprio(0);                                         \
    }

// pair p (p=0..12): stage tiles 2p+6, 2p+7; wait keeping 12 in flight;
// two fence-free compute iters.
#define PAIR(p)                                                                \
    STAGE(2 * (p) + 6) STAGE(2 * (p) + 7)                                      \
    WAITV(12);                                                                 \
    KSTEP(2 * (p)) KSTEP(2 * (p) + 1)

    PAIR(0)  PAIR(1)  PAIR(2)  PAIR(3)
    PAIR(4)  PAIR(5)  PAIR(6)  PAIR(7)
    PAIR(8)  PAIR(9)  PAIR(10) PAIR(11)
    PAIR(12)
    // tail: nothing left to stage; drain 12 -> 8 -> 4 -> 0
    WAITV(8);
    KSTEP(26) KSTEP(27)
    WAITV(4);
    KSTEP(28) KSTEP(29)
    WAITV(0);
    KSTEP(30) KSTEP(31)
#undef PAIR
#undef KSTEP
#undef STAGE
#undef WAITV

    // fence: keep epilogue VMEM (bn loads, stores) out of the loop region
    __builtin_amdgcn_sched_barrier(0);

    // ---------------- epilogue: BN + ReLU + coalesced store ------------------
    // C layout: col = lane&31, row = (r&3) + 8*(r>>2) + 4*lh
#pragma unroll
    for (int r = 0; r < 16; ++r) {
        int o = ot * 32 + (r & 3) + ((r >> 2) << 3) + (lh << 2);
        float gs = bn_g[o] * BNSCL, bb = bn_b[o];
        size_t row = (size_t)(b * 64 + o) << 15;
        out[row + pc0] = fmaxf(acc0[r] * gs + bb, 0.f);
        out[row + pc1] = fmaxf(acc1[r] * gs + bb, 0.f);
    }
}

// ---------------------------------------------------------------------------
extern "C" void kernel_launch(void* const* d_in, const int* in_sizes, int n_in,
                              void* d_out, int out_size, void* d_ws, size_t ws_size,
                              hipStream_t stream)
{
    const float* features = (const float*)d_in[0];
    const float* xyz      = (const float*)d_in[1];
    const float* w1  = (const float*)d_in[2];
    const float* g1  = (const float*)d_in[3];
    const float* be1 = (const float*)d_in[4];
    const float* w2  = (const float*)d_in[5];
    const float* g2  = (const float*)d_in[6];
    const float* be2 = (const float*)d_in[7];
    const float* w3  = (const float*)d_in[8];
    const float* g3  = (const float*)d_in[9];
    const float* be3 = (const float*)d_in[10];
    const float* w4  = (const float*)d_in[11];
    const float* b4  = (const float*)d_in[12];
    const float* wb  = (const float*)d_in[13];
    const float* bn_g = (const float*)d_in[14];
    const float* bn_b = (const float*)d_in[15];

    f16* scores = (f16*)d_ws;                             // 4 MB
    f16* wbtA   = (f16*)((char*)d_ws + (4u << 20));       // 128 KB

    k_scores<<<512, 256, 0, stream>>>(xyz, w1, g1, be1, w2, g2, be2,
                                      w3, g3, be3, w4, b4, wb, wbtA, scores);
    k_main<<<512, 1024, 0, stream>>>(features, scores, wbtA, bn_g, bn_b,
                                     (float*)d_out);
}

// Round 8
// 171.001 us; speedup vs baseline: 1.0601x; 1.0601x over previous
//
#include <hip/hip_runtime.h>
#include <hip/hip_bf16.h>

typedef _Float16 f16;
typedef __attribute__((ext_vector_type(2))) _Float16 f16x2;
typedef __attribute__((ext_vector_type(8))) _Float16 f16x8;
typedef __attribute__((ext_vector_type(16))) float f32x16;

#define BNSCL 0.9999950000375f   /* 1/sqrt(1+1e-5) */

// ---------------------------------------------------------------------------
// Kernel 1: per-point scores MLP + softmax (weights in LDS, 2 pts/thread),
// output f16x8 per point. Fused: blocks < 256 build the weight bank in MFMA
// A-fragment order, f16, TWO banks:
//   bank 0 (S): wb_diff + wb_raw combined  (main-term weights)
//   bank 1 (D): wb_diff only               (center-correction weights)
//   wbtA[((ot*64 + bank*32 + ks)*64 + lane)*8 + j]
//     with c = ks*2 + (lane>>5) in [0,64), o = ot*32 + (lane&31):
//     S: wb[c][j][o] + wb[c+64][j][o]  (summed in f32, then f16)
//     D: wb[c][j][o]
// ---------------------------------------------------------------------------
__global__ __launch_bounds__(256) void k_scores(
    const float* __restrict__ xyz,
    const float* __restrict__ w1, const float* __restrict__ g1, const float* __restrict__ be1,
    const float* __restrict__ w2, const float* __restrict__ g2, const float* __restrict__ be2,
    const float* __restrict__ w3, const float* __restrict__ g3, const float* __restrict__ be3,
    const float* __restrict__ w4, const float* __restrict__ b4,
    const float* __restrict__ wb, f16* __restrict__ wbtA,
    f16* __restrict__ scores)
{
    __shared__ float lw[856];
    const int tid = threadIdx.x;

    // fused weight-bank fragment-order transpose (1 elem/thread, blocks 0-255)
    if (blockIdx.x < 256) {
        int idx = blockIdx.x * 256 + tid;       // 0..65535
        int j    = idx & 7;
        int lane = (idx >> 3) & 63;
        int ks   = (idx >> 9) & 31;
        int bank = (idx >> 14) & 1;             // 0 = S (combined), 1 = D
        int ot   = idx >> 15;
        int c    = ks * 2 + (lane >> 5);        // 0..63
        int o    = ot * 32 + (lane & 31);
        float vD = wb[(c * 8 + j) * 64 + o];
        float v  = bank ? vD : vD + wb[((c + 64) * 8 + j) * 64 + o];
        wbtA[idx] = (f16)v;
    }

    if (tid < 112) lw[tid] = w1[tid];
    lw[112 + tid] = w2[tid];
    lw[368 + tid] = w3[tid];
    if (tid < 128) lw[624 + tid] = w4[tid];
    if (tid < 8)   lw[752 + tid] = b4[tid];
    if (tid < 16) {
        lw[760 + tid] = g1[tid] * BNSCL;  lw[776 + tid] = be1[tid];
        lw[792 + tid] = g2[tid] * BNSCL;  lw[808 + tid] = be2[tid];
        lw[824 + tid] = g3[tid] * BNSCL;  lw[840 + tid] = be3[tid];
    }
    __syncthreads();

    float in7[2][7], h1[2][16], h2[2][16], s[2][8];

#pragma unroll
    for (int q = 0; q < 2; ++q) {
        int g = blockIdx.x * 512 + q * 256 + tid;
        int b = g >> 15;
        int p = g & 32767;
        int pc = p & ~31;
        const float* xb = xyz + (size_t)b * 98304;
        float cx = xb[pc], cy = xb[32768 + pc], cz = xb[65536 + pc];
        float dx = xb[p] - cx, dy = xb[32768 + p] - cy, dz = xb[65536 + p] - cz;
        in7[q][0] = cx; in7[q][1] = cy; in7[q][2] = cz;
        in7[q][3] = dx; in7[q][4] = dy; in7[q][5] = dz;
        in7[q][6] = sqrtf(dx * dx + dy * dy + dz * dz);
    }

#pragma unroll
    for (int o = 0; o < 16; ++o) {
        float a0 = 0.f, a1 = 0.f;
#pragma unroll
        for (int c = 0; c < 7; ++c) {
            float w = lw[o * 7 + c];
            a0 += w * in7[0][c]; a1 += w * in7[1][c];
        }
        float gs = lw[760 + o], bb = lw[776 + o];
        h1[0][o] = fmaxf(a0 * gs + bb, 0.f);
        h1[1][o] = fmaxf(a1 * gs + bb, 0.f);
    }
#pragma unroll
    for (int o = 0; o < 16; ++o) {
        float a0 = 0.f, a1 = 0.f;
#pragma unroll
        for (int c = 0; c < 16; ++c) {
            float w = lw[112 + o * 16 + c];
            a0 += w * h1[0][c]; a1 += w * h1[1][c];
        }
        float gs = lw[792 + o], bb = lw[808 + o];
        h2[0][o] = fmaxf(a0 * gs + bb, 0.f);
        h2[1][o] = fmaxf(a1 * gs + bb, 0.f);
    }
#pragma unroll
    for (int o = 0; o < 16; ++o) {
        float a0 = 0.f, a1 = 0.f;
#pragma unroll
        for (int c = 0; c < 16; ++c) {
            float w = lw[368 + o * 16 + c];
            a0 += w * h2[0][c]; a1 += w * h2[1][c];
        }
        float gs = lw[824 + o], bb = lw[840 + o];
        h1[0][o] = fmaxf(a0 * gs + bb, 0.f);
        h1[1][o] = fmaxf(a1 * gs + bb, 0.f);
    }
#pragma unroll
    for (int o = 0; o < 8; ++o) {
        float bb = lw[752 + o];
        float a0 = bb, a1 = bb;
#pragma unroll
        for (int c = 0; c < 16; ++c) {
            float w = lw[624 + o * 16 + c];
            a0 += w * h1[0][c]; a1 += w * h1[1][c];
        }
        s[0][o] = a0; s[1][o] = a1;
    }

#pragma unroll
    for (int q = 0; q < 2; ++q) {
        int g = blockIdx.x * 512 + q * 256 + tid;
        float mx = s[q][0];
#pragma unroll
        for (int i = 1; i < 8; ++i) mx = fmaxf(mx, s[q][i]);
        float sum = 0.f;
#pragma unroll
        for (int i = 0; i < 8; ++i) { s[q][i] = __expf(s[q][i] - mx); sum += s[q][i]; }
        float inv = 1.f / sum;
        f16x8 o8;
#pragma unroll
        for (int i = 0; i < 8; ++i) o8[i] = (f16)(s[q][i] * inv);
        *(f16x8*)(scores + (size_t)g * 8) = o8;
    }
}

// ---------------------------------------------------------------------------
// Kernel 2: main einsum, 32x32x16 f16 MFMA.
// ROUND 8: algebraic bank-fold. Six schedule variants all plateaued at
// 52-57 us -> the per-iter WORK is the limiter, not the schedule. Identity:
//   sum_c (f-fc)*wD + f*wR  =  sum_c f*(wD+wR)  -  sum_c fc*wD.
// Term 1: A = combined bank wS (bank 0), B = f*s  -> 2 MFMA + 1 ds_read_b128
// per iter (was 4 MFMA + 2 reads). Term 2 depends only on the group center:
// corr[o,nk] = sum_m s[nk,m]*G[g][m,o], G[g][m,o] = sum_c fc[c,g]*wbD[c,m,o].
// G accumulated in-loop with 1 extra MFMA (A = wbD bank 1; B = diagonal mask:
// col g*8+m gets -fc[channel, g] at slot m, cols>=16 zero) into accG.
// Epilogue: accG (=-G, C/D layout) bounced through 1 KB/wave LDS into
// A-fragment layout [g][o][m]; corr applied with 2 MFMAs whose B is the
// resident score regs, half-zeroed (k-slots lh=0 -> acc0/G0, lh=1 -> acc1/G1).
// Net/wave: MFMA 128 -> 98, in-loop muls 16 -> 12, subtracts gone.
// Schedule = round 6 exactly (distance-6 DMA, WAITV(12), barrier-free feat);
// round-7 stagger/setprio reverted (regressed).
// ---------------------------------------------------------------------------
__global__ __launch_bounds__(1024, 4) void k_main(
    const float* __restrict__ feat,
    const f16* __restrict__ scores,
    const f16* __restrict__ wbtA,
    const float* __restrict__ bn_g, const float* __restrict__ bn_b,
    float* __restrict__ out)
{
    __shared__ __align__(16) f16 lwb[32768];         // 64 KB weights (S+D banks)
    __shared__ __align__(16) float fbuf[8][2][1024]; // 64 KB feat 8-slot buf
    __shared__ __align__(16) f16 gscr[16][512];      // 16 KB G-redistribute

    const int tid  = threadIdx.x;
    const int lane = tid & 63;
    const int wave = tid >> 6;          // 0..15
    const int l31  = lane & 31;
    const int lh   = lane >> 5;         // 0..1
    const int w64  = wave * 64;

    const int ot = blockIdx.x >> 8;             // 0..1 (o-tile half)
    const int g  = blockIdx.x & 255;            // point-group
    const int pblock = g * 1024;                // global point base
    const int b    = pblock >> 15;
    const int pt0  = (pblock & 32767) + w64;    // within-batch, 32-aligned
    const int pc0  = pt0 + l31;
    const int pc1  = pc0 + 32;

    const float* fb = feat + (size_t)b * 2097152;    // (64, 32768)
    // per-lane DMA source base: this wave's 64-pt window, row 0
    const float* gsrc0 = fb + (pblock & 32767) + w64 + lane;

    // ---- stage this ot's 64 KB of fragment-ordered weights into LDS ----
    const f16* src = wbtA + ((size_t)ot << 15);      // 32768 f16
#pragma unroll
    for (int it = 0; it < 4; ++it) {
        int idx = it * 1024 + tid;                   // 0..4095 16B-chunks
        *(int4*)&lwb[idx << 3] = *(const int4*)&src[idx << 3];
    }

    // ---- scores: load + extract to registers (consumed before loop) ----
    const int gpt = pblock + w64 + l31;
    f16x8 sv0 = *(const f16x8*)(scores + (size_t)gpt * 8);
    f16x8 sv1 = *(const f16x8*)(scores + (size_t)(gpt + 32) * 8);
    const f16x2 s0a = {sv0[0], sv0[1]}, s0b = {sv0[2], sv0[3]},
                s0c = {sv0[4], sv0[5]}, s0d = {sv0[6], sv0[7]};
    const f16x2 s1a = {sv1[0], sv1[1]}, s1b = {sv1[2], sv1[3]},
                s1c = {sv1[4], sv1[5]}, s1d = {sv1[6], sv1[7]};

    // diagonal-mask pairs for the G-MFMA B-fragment: lane col l31 (<16)
    // contributes slot m = l31&7 for group g = l31>>3; other cols zero.
    const bool mon  = (l31 < 16);
    const int  mpos = l31 & 7;
    const f16x2 mk0 = { (f16)((mon && mpos == 0) ? 1.f : 0.f),
                        (f16)((mon && mpos == 1) ? 1.f : 0.f) };
    const f16x2 mk1 = { (f16)((mon && mpos == 2) ? 1.f : 0.f),
                        (f16)((mon && mpos == 3) ? 1.f : 0.f) };
    const f16x2 mk2 = { (f16)((mon && mpos == 4) ? 1.f : 0.f),
                        (f16)((mon && mpos == 5) ? 1.f : 0.f) };
    const f16x2 mk3 = { (f16)((mon && mpos == 6) ? 1.f : 0.f),
                        (f16)((mon && mpos == 7) ? 1.f : 0.f) };

    f32x16 acc0 = {}, acc1 = {}, accG = {};
    const f16* Alds = lwb + (lane << 3);             // lane's 16B slot

// DMA one kk-step's feat tile (rows 2kk, 2kk+1; this wave's 64 points) into
// fbuf[kk & 7]. Wave-uniform LDS dest + lane*4; per-lane global src.
#define STAGE(t)                                                               \
    {                                                                          \
        __builtin_amdgcn_global_load_lds(                                      \
            (const __attribute__((address_space(1))) void*)                    \
                (gsrc0 + ((size_t)(2 * (t)) << 15)),                           \
            (__attribute__((address_space(3))) void*)&fbuf[(t) & 7][0][w64],   \
            4, 0, 0);                                                          \
        __builtin_amdgcn_global_load_lds(                                      \
            (const __attribute__((address_space(1))) void*)                    \
                (gsrc0 + ((size_t)(2 * (t) + 1) << 15)),                       \
            (__attribute__((address_space(3))) void*)&fbuf[(t) & 7][1][w64],   \
            4, 0, 0);                                                          \
    }

#define WAITV(n) asm volatile("s_waitcnt vmcnt(" #n ")" ::: "memory")

    // keep pre-loop loads/extracts above; then prologue DMA tiles 0..5
    __builtin_amdgcn_sched_barrier(0);
    STAGE(0); STAGE(1); STAGE(2); STAGE(3); STAGE(4); STAGE(5);

    // weights visible to all waves; prologue DMAs stay in flight (raw barrier)
    asm volatile("s_waitcnt lgkmcnt(0)" ::: "memory");
    __builtin_amdgcn_s_barrier();

// one compute iteration (no fences inside) -------------------------------
// aS = combined bank (term 1), aD = diff bank (G accumulation).
#define KSTEP(kk)                                                              \
    {                                                                          \
        f16x8 aS = *(const f16x8*)(Alds + ((size_t)(kk) << 9));                \
        f16x8 aD = *(const f16x8*)(Alds + ((size_t)((kk) + 32) << 9));         \
        const float* frow = fbuf[(kk) & 7][lh];                                \
        float fv0 = frow[w64 + l31], fv1 = frow[w64 + l31 + 32];               \
        float fc0 = frow[w64],       fc1 = frow[w64 + 32];                     \
        float fcs = (l31 & 8) ? fc1 : fc0;                                     \
        f16 hR0 = (f16)fv0, hR1 = (f16)fv1, hC = (f16)(-fcs);                  \
        f16x2 fR0 = {hR0, hR0}, fR1 = {hR1, hR1}, fg2 = {hC, hC};              \
        f16x2 r0a = fR0 * s0a, r0b = fR0 * s0b, r0c = fR0 * s0c, r0d = fR0 * s0d; \
        f16x2 r1a = fR1 * s1a, r1b = fR1 * s1b, r1c = fR1 * s1c, r1d = fR1 * s1d; \
        f16x2 q0 = mk0 * fg2, q1 = mk1 * fg2, q2 = mk2 * fg2, q3 = mk3 * fg2;  \
        f16x8 bS0 = {r0a[0],r0a[1],r0b[0],r0b[1],r0c[0],r0c[1],r0d[0],r0d[1]}; \
        f16x8 bS1 = {r1a[0],r1a[1],r1b[0],r1b[1],r1c[0],r1c[1],r1d[0],r1d[1]}; \
        f16x8 bG  = {q0[0],q0[1],q1[0],q1[1],q2[0],q2[1],q3[0],q3[1]};         \
        acc0 = __builtin_amdgcn_mfma_f32_32x32x16_f16(aS, bS0, acc0, 0, 0, 0); \
        acc1 = __builtin_amdgcn_mfma_f32_32x32x16_f16(aS, bS1, acc1, 0, 0, 0); \
        accG = __builtin_amdgcn_mfma_f32_32x32x16_f16(aD, bG, accG, 0, 0, 0);  \
    }

// pair p (p=0..12): stage tiles 2p+6, 2p+7; wait keeping 12 in flight;
// two fence-free compute iters.
#define PAIR(p)                                                                \
    STAGE(2 * (p) + 6) STAGE(2 * (p) + 7)                                      \
    WAITV(12);                                                                 \
    KSTEP(2 * (p)) KSTEP(2 * (p) + 1)

    PAIR(0)  PAIR(1)  PAIR(2)  PAIR(3)
    PAIR(4)  PAIR(5)  PAIR(6)  PAIR(7)
    PAIR(8)  PAIR(9)  PAIR(10) PAIR(11)
    PAIR(12)
    // tail: nothing left to stage; drain 12 -> 8 -> 4 -> 0
    WAITV(8);
    KSTEP(26) KSTEP(27)
    WAITV(4);
    KSTEP(28) KSTEP(29)
    WAITV(0);
    KSTEP(30) KSTEP(31)
#undef PAIR
#undef KSTEP
#undef STAGE
#undef WAITV

    // ---- center-correction: redistribute accG (=-G) into A-fragment layout
    // via this wave's private 1 KB LDS region, then 2 corr-MFMAs.
    // accG C/D layout: col=l31 (= g*8+m for col<16), row o = (r&3)+8*(r>>2)+4*lh.
    if (l31 < 16) {
        const int base = (l31 >> 3) * 256 + (l31 & 7);   // g*256 + m
#pragma unroll
        for (int r = 0; r < 16; ++r) {
            int o = (r & 3) + ((r >> 2) << 3) + (lh << 2);
            gscr[wave][base + o * 8] = (f16)accG[r];
        }
    }
    asm volatile("s_waitcnt lgkmcnt(0)" ::: "memory");
    __builtin_amdgcn_sched_barrier(0);
    {
        // A2: lane holds (-G)[g=lh][o=l31][m=0..7]; k-slot lh*8+m -> (g,m).
        f16x8 a2 = *(const f16x8*)&gscr[wave][lh * 256 + l31 * 8];
        f16x8 z8 = {};
        f16x8 bC0 = lh ? z8 : sv0;      // k-slots g=0 get s0, g=1 zero
        f16x8 bC1 = lh ? sv1 : z8;      // k-slots g=1 get s1, g=0 zero
        acc0 = __builtin_amdgcn_mfma_f32_32x32x16_f16(a2, bC0, acc0, 0, 0, 0);
        acc1 = __builtin_amdgcn_mfma_f32_32x32x16_f16(a2, bC1, acc1, 0, 0, 0);
    }

    // fence: keep epilogue VMEM (bn loads, stores) out of the loop region
    __builtin_amdgcn_sched_barrier(0);

    // ---------------- epilogue: BN + ReLU + coalesced store ------------------
    // C layout: col = lane&31, row = (r&3) + 8*(r>>2) + 4*lh
#pragma unroll
    for (int r = 0; r < 16; ++r) {
        int o = ot * 32 + (r & 3) + ((r >> 2) << 3) + (lh << 2);
        float gs = bn_g[o] * BNSCL, bb = bn_b[o];
        size_t row = (size_t)(b * 64 + o) << 15;
        out[row + pc0] = fmaxf(acc0[r] * gs + bb, 0.f);
        out[row + pc1] = fmaxf(acc1[r] * gs + bb, 0.f);
    }
}

// ---------------------------------------------------------------------------
extern "C" void kernel_launch(void* const* d_in, const int* in_sizes, int n_in,
                              void* d_out, int out_size, void* d_ws, size_t ws_size,
                              hipStream_t stream)
{
    const float* features = (const float*)d_in[0];
    const float* xyz      = (const float*)d_in[1];
    const float* w1  = (const float*)d_in[2];
    const float* g1  = (const float*)d_in[3];
    const float* be1 = (const float*)d_in[4];
    const float* w2  = (const float*)d_in[5];
    const float* g2  = (const float*)d_in[6];
    const float* be2 = (const float*)d_in[7];
    const float* w3  = (const float*)d_in[8];
    const float* g3  = (const float*)d_in[9];
    const float* be3 = (const float*)d_in[10];
    const float* w4  = (const float*)d_in[11];
    const float* b4  = (const float*)d_in[12];
    const float* wb  = (const float*)d_in[13];
    const float* bn_g = (const float*)d_in[14];
    const float* bn_b = (const float*)d_in[15];

    f16* scores = (f16*)d_ws;                             // 4 MB
    f16* wbtA   = (f16*)((char*)d_ws + (4u << 20));       // 128 KB

    k_scores<<<512, 256, 0, stream>>>(xyz, w1, g1, be1, w2, g2, be2,
                                      w3, g3, be3, w4, b4, wb, wbtA, scores);
    k_main<<<512, 1024, 0, stream>>>(features, scores, wbtA, bn_g, bn_b,
                                     (float*)d_out);
}